// Round 1
// baseline (285.729 us; speedup 1.0000x reference)
//
#include <hip/hip_runtime.h>

typedef unsigned short u16;
typedef unsigned int u32;

#define NC 50000
#define NN 10000
#define NG 20000
#define NE 100000
#define NSCAN 150016   // 5 dst-count regions (150,000) padded
#define NBLK 74        // ceil(NSCAN / 2048)

// CSR dst regions inside hist/bases (element offsets):
// pins_dst    [0,      10000)   -> net rows    (gc payload)
// connect_dst [10000,  30000)   -> gcell rows  (gc payload)
// pt_dst      [30000,  50000)   -> gcell rows  (gc payload)
// pinned_dst  [50000, 100000)   -> cell rows   (nn payload, pos-300000)
// pf_dst      [100000,150000)   -> cell rows   (nn payload, pos-300000)

// ---------- bf16 helpers (workspace T tables only) ----------
__device__ __forceinline__ float bflo(u32 a) { return __uint_as_float(a << 16); }
__device__ __forceinline__ float bfhi(u32 a) { return __uint_as_float(a & 0xFFFF0000u); }
__device__ __forceinline__ u16 fbf(float f) {
  u32 u = __float_as_uint(f);
  return (u16)((u + 0x7FFFu + ((u >> 16) & 1u)) >> 16);  // RNE
}

// one NNConv edge message for lane-output o
__device__ __forceinline__ float nn_msg(int e, int s, const float* __restrict__ ef,
                                        const u16* __restrict__ T,
                                        const float* __restrict__ C, int o) {
  const float4* efp = reinterpret_cast<const float4*>(ef + (size_t)e * 16);
  float4 ea = efp[0], eb = efp[1], ec = efp[2], ed = efp[3];
  const uint4* tp = reinterpret_cast<const uint4*>(T + (size_t)s * 512 + o * 16);
  uint4 ta = tp[0], tb = tp[1];
  float m = C[(size_t)s * 32 + o];
  m += ea.x * bflo(ta.x) + ea.y * bfhi(ta.x) + ea.z * bflo(ta.y) + ea.w * bfhi(ta.y);
  m += eb.x * bflo(ta.z) + eb.y * bfhi(ta.z) + eb.z * bflo(ta.w) + eb.w * bfhi(ta.w);
  m += ec.x * bflo(tb.x) + ec.y * bfhi(tb.x) + ec.z * bflo(tb.y) + ec.w * bfhi(tb.y);
  m += ed.x * bflo(tb.z) + ed.y * bfhi(tb.z) + ed.z * bflo(tb.w) + ed.w * bfhi(tb.w);
  return m;
}

// ---------- K_FRONT: transform (469) | C (1875) | hist (196) ----------
// transform: register-blocked GEMM tile, 64 nodes/block, 2 j-outputs/thread.
//   LDS-staged h tile (one sync), w in 64 VGPRs, FMA-bound inner loop.
__global__ __launch_bounds__(512) void k_front(
    const float* __restrict__ feat_net, const float* __restrict__ feat_han,
    const float* __restrict__ W_topo, const float* __restrict__ b_topo,
    u16* __restrict__ T_net, u16* __restrict__ T_han,
    float* __restrict__ C_net, float* __restrict__ C_han,
    const int* __restrict__ pins_src, const int* __restrict__ pins_dst,
    const int* __restrict__ pinned_dst, const int* __restrict__ pf_dst,
    const int* __restrict__ connect_src, const int* __restrict__ connect_dst,
    const int* __restrict__ pt_src, const int* __restrict__ pt_dst,
    int* __restrict__ hist, int* __restrict__ srccnt) {
  int b = blockIdx.x;
  int tid = threadIdx.x;
  if (b < 469) {  // ---- transform: nodes [b*64, b*64+64) of 30000 ----
    __shared__ float hs[64][32];  // 8 KB
    int nd0 = b * 64;
    {  // stage: thread t loads float4 at element t*4 of the 64x32 tile
      int idx = tid * 4;
      int nl = idx >> 5, i = idx & 31;
      int ng = nd0 + nl;
      int ngc = min(ng, 29999);  // clamp (rows >= 30000 unused)
      const float* rp = (ngc < NN) ? feat_net + (size_t)ngc * 32
                                   : feat_han + (size_t)(ngc - NN) * 32;
      *reinterpret_cast<float4*>(&hs[nl][i]) =
          *reinterpret_cast<const float4*>(rp + i);
    }
    // w regs for j0 = 2*(tid&255), j1 = j0+1
    int jj = tid & 255;
    int j0 = jj * 2, j1 = j0 + 1;
    int p0 = j0 & 15, o0 = j0 >> 4;
    int p1 = j1 & 15, o1 = j1 >> 4;
    float w0[32], w1[32];
#pragma unroll
    for (int i = 0; i < 32; i++) {
      w0[i] = W_topo[p0 * 1024 + i * 32 + o0];
      w1[i] = W_topo[p1 * 1024 + i * 32 + o1];
    }
    __syncthreads();
    int g = tid >> 8;  // node half: 0 or 1 (wave-uniform)
#pragma unroll 4
    for (int n = 0; n < 32; n++) {
      int nl = g * 32 + n;
      float a0 = 0.f, a1 = 0.f;
#pragma unroll
      for (int i = 0; i < 32; i++) {
        float h = hs[nl][i];  // wave-uniform -> LDS broadcast
        a0 += h * w0[i];
        a1 += h * w1[i];
      }
      int s = nd0 + nl;
      if (s < 30000) {
        u32 pk = (u32)fbf(a0) | ((u32)fbf(a1) << 16);
        u32* dst = (s < NN)
            ? reinterpret_cast<u32*>(T_net + (size_t)s * 512 + j0)
            : reinterpret_cast<u32*>(T_han + (size_t)(s - NN) * 512 + j0);
        *dst = pk;
      }
    }
    return;
  }
  if (b < 2344) {  // ---- C: (NN+NG)*32 = 960,000 = 1875*512 exact ----
    int t = (b - 469) * 512 + tid;
    int s2 = t >> 5, o = t & 31;
    bool han = s2 >= NN;
    const float* feat = han ? feat_han : feat_net;
    float* C = han ? C_han : C_net;
    int s = han ? s2 - NN : s2;
    float acc = 0.f;
#pragma unroll 8
    for (int i = 0; i < 32; i++)
      acc += feat[(size_t)s * 32 + i] * b_topo[i * 32 + o];
    C[(size_t)s * 32 + o] = acc;
    return;
  }
  // ---- hist ----
  int e = (b - 2344) * 512 + tid;
  if (e >= NE) return;
  atomicAdd(&hist[pins_dst[e]], 1);
  atomicAdd(&hist[10000 + connect_dst[e]], 1);
  atomicAdd(&hist[30000 + pt_dst[e]], 1);
  atomicAdd(&hist[50000 + pinned_dst[e]], 1);
  atomicAdd(&hist[100000 + pf_dst[e]], 1);
  atomicAdd(&srccnt[pins_src[e]], 1);            // cell  [0,50000)
  atomicAdd(&srccnt[50000 + connect_src[e]], 1); // gcell [50000,70000)
  atomicAdd(&srccnt[70000 + pt_src[e]], 1);      // cell  [70000,120000)
}

// ---------- scan (2 kernels) ----------
__global__ __launch_bounds__(256) void k_scan1(
    const int* __restrict__ cnt, int* __restrict__ bsum) {
  __shared__ int sm[256];
  int b = blockIdx.x, tid = threadIdx.x;
  int base = b * 2048 + tid * 8;
  int tot = 0;
#pragma unroll
  for (int j = 0; j < 8; j++) {
    int i = base + j;
    tot += (i < NSCAN) ? cnt[i] : 0;
  }
  sm[tid] = tot;
  __syncthreads();
  for (int off = 128; off > 0; off >>= 1) {
    if (tid < off) sm[tid] += sm[tid + off];
    __syncthreads();
  }
  if (tid == 0) bsum[b] = sm[0];
}

__global__ __launch_bounds__(256) void k_scan3(
    const int* __restrict__ cnt, const int* __restrict__ bsum,
    int* __restrict__ bases) {
  __shared__ int sm[256];
  __shared__ int carry;
  int b = blockIdx.x, tid = threadIdx.x;
  if (tid == 0) {
    int run = 0;
    for (int i = 0; i < b; i++) run += bsum[i];
    carry = run;
  }
  int base = b * 2048 + tid * 8;
  int v[8];
  int tot = 0;
#pragma unroll
  for (int j = 0; j < 8; j++) {
    int i = base + j;
    v[j] = (i < NSCAN) ? cnt[i] : 0;
    tot += v[j];
  }
  sm[tid] = tot;
  __syncthreads();
  for (int off = 1; off < 256; off <<= 1) {
    int add = (tid >= off) ? sm[tid - off] : 0;
    __syncthreads();
    sm[tid] += add;
    __syncthreads();
  }
  int excl = sm[tid] - tot + carry;
#pragma unroll
  for (int j = 0; j < 8; j++) {
    int i = base + j;
    if (i < NSCAN) bases[i] = excl;
    excl += v[j];
  }
}

// ---------- K_FILL: payload CSRs ----------
// gc (rel 0..2): csr_gc[pos] = (src, bits(rsqrt(deg_src)))   -- 8B sequential payload
// nn (rel 3..4): csr_nn[pos-300000] = (e, src)
__global__ __launch_bounds__(512) void k_fill(
    const int* __restrict__ pins_src, const int* __restrict__ pins_dst,
    const int* __restrict__ connect_src, const int* __restrict__ connect_dst,
    const int* __restrict__ pt_src, const int* __restrict__ pt_dst,
    const int* __restrict__ pinned_src, const int* __restrict__ pinned_dst,
    const int* __restrict__ pf_src, const int* __restrict__ pf_dst,
    const int* __restrict__ srccnt,
    const int* __restrict__ bases, int* __restrict__ cursor,
    int2* __restrict__ csr_gc, int2* __restrict__ csr_nn) {
  int t = blockIdx.x * 512 + threadIdx.x;
  if (t >= 5 * NE) return;
  int r = (t >= NE) + (t >= 2 * NE) + (t >= 3 * NE) + (t >= 4 * NE);
  int e = t - r * NE;
  const int* srcs = r == 0 ? pins_src : r == 1 ? connect_src
                   : r == 2 ? pt_src : r == 3 ? pinned_src : pf_src;
  const int* dsts = r == 0 ? pins_dst : r == 1 ? connect_dst
                   : r == 2 ? pt_dst : r == 3 ? pinned_dst : pf_dst;
  int off = r == 0 ? 0 : r == 1 ? 10000 : r == 2 ? 30000 : r == 3 ? 50000 : 100000;
  int s = srcs[e];
  int g = off + dsts[e];
  int pos = atomicAdd(&cursor[g], 1);
  int cpos = bases[g] + pos;
  if (r < 3) {
    int soff = r == 0 ? 0 : r == 1 ? 50000 : 70000;
    float w = rsqrtf(fmaxf((float)srccnt[soff + s], 1.f));
    csr_gc[cpos] = make_int2(s, __float_as_int(w));
  } else {
    csr_nn[cpos - 300000] = make_int2(e, s);
  }
}

// ---------- K_GC: graph-conv gather (payload CSR: 1 random load/edge) ----------
__global__ __launch_bounds__(512) void k_gc_gather(
    const int* __restrict__ hist, const int* __restrict__ bases,
    const int2* __restrict__ csr_gc,
    const float* __restrict__ node_feat, const float* __restrict__ hanna_feat,
    float* __restrict__ S_net, float* __restrict__ S_conn, float* __restrict__ S_pt) {
  int t = blockIdx.x * 512 + threadIdx.x;  // 3125*512 = 1.6M exact
  int rr = t >> 5, o = t & 31;
  int rel = (rr >= 10000) + (rr >= 30000);
  const float* feat = (rel == 1) ? hanna_feat : node_feat;
  float* S = rel == 0 ? S_net + (size_t)rr * 32
           : rel == 1 ? S_conn + (size_t)(rr - 10000) * 32
                      : S_pt + (size_t)(rr - 30000) * 32;
  int base = bases[rr], deg = hist[rr];
  float acc = 0.f;
  int k = 0;
  for (; k + 1 < deg; k += 2) {
    int2 pa = csr_gc[base + k], pb = csr_gc[base + k + 1];
    acc += feat[(size_t)pa.x * 32 + o] * __int_as_float(pa.y) +
           feat[(size_t)pb.x * 32 + o] * __int_as_float(pb.y);
  }
  if (k < deg) {
    int2 pa = csr_gc[base + k];
    acc += feat[(size_t)pa.x * 32 + o] * __int_as_float(pa.y);
  }
  S[o] = acc;
}

// ---------- K_TAIL: nn_gather cells (3125) | net fin (625) | gcell fin (1250) ----------
__global__ __launch_bounds__(512) void k_tail(
    const int* __restrict__ hist, const int* __restrict__ bases,
    const int2* __restrict__ csr_nn,
    const float* __restrict__ pin_feat, const float* __restrict__ edge_feat,
    const u16* __restrict__ T_net, const u16* __restrict__ T_han,
    const float* __restrict__ C_net, const float* __restrict__ C_han,
    const float* __restrict__ b_pinned, const float* __restrict__ b_pf,
    const float* __restrict__ S_net, const float* __restrict__ net_feat,
    const float* __restrict__ W_pins, const float* __restrict__ b_pins,
    const float* __restrict__ W_net, const float* __restrict__ b_net,
    const float* __restrict__ S_conn, const float* __restrict__ S_pt,
    const float* __restrict__ W_connect, const float* __restrict__ b_connect,
    const float* __restrict__ W_pt, const float* __restrict__ b_pt,
    float* __restrict__ out) {
  __shared__ float Wa[1024], Wb[1024];
  int b = blockIdx.x;
  if (b < 3125) {  // ---- NNConv gather: NC*32 = 1.6M = 3125*512 exact ----
    int t = b * 512 + threadIdx.x;
    int d = t >> 5, o = t & 31;
    float a0 = 0.f, a1 = 0.f;
    {  // conv0: 'pinned' net -> cell
      int g = 50000 + d;
      int base = bases[g] - 300000, deg = hist[g];
      int k = 0;
      for (; k + 1 < deg; k += 2) {
        int2 ea = csr_nn[base + k], eb = csr_nn[base + k + 1];
        a0 += nn_msg(ea.x, ea.y, pin_feat, T_net, C_net, o) +
              nn_msg(eb.x, eb.y, pin_feat, T_net, C_net, o);
      }
      if (k < deg) {
        int2 ea = csr_nn[base + k];
        a0 += nn_msg(ea.x, ea.y, pin_feat, T_net, C_net, o);
      }
      a0 /= fmaxf((float)deg, 1.f);
    }
    {  // conv1: 'point-from' gcell -> cell
      int g = 100000 + d;
      int base = bases[g] - 300000, deg = hist[g];
      int k = 0;
      for (; k + 1 < deg; k += 2) {
        int2 ea = csr_nn[base + k], eb = csr_nn[base + k + 1];
        a1 += nn_msg(ea.x, ea.y, edge_feat, T_han, C_han, o) +
              nn_msg(eb.x, eb.y, edge_feat, T_han, C_han, o);
      }
      if (k < deg) {
        int2 ea = csr_nn[base + k];
        a1 += nn_msg(ea.x, ea.y, edge_feat, T_han, C_han, o);
      }
      a1 /= fmaxf((float)deg, 1.f);
    }
    out[(size_t)d * 32 + o] = a0 + a1 + b_pinned[o] + b_pf[o];
    return;
  }
  if (b < 3750) {  // ---- net fin: NN*32 = 320,000 = 625*512 exact ----
    for (int k = threadIdx.x; k < 1024; k += 512) {
      Wa[k] = W_pins[k];
      Wb[k] = W_net[k];
    }
    __syncthreads();
    int t = (b - 3125) * 512 + threadIdx.x;
    int r = t >> 5, o = t & 31;
    float a1 = 0.f, a2 = 0.f;
#pragma unroll 8
    for (int i = 0; i < 32; i++) {
      a1 += S_net[(size_t)r * 32 + i] * Wa[i * 32 + o];
      a2 += net_feat[(size_t)r * 32 + i] * Wb[i * 32 + o];
    }
    out[1600000 + t] = a1 * rsqrtf(fmaxf((float)hist[r], 1.f)) + b_pins[o] +
                       a2 + b_net[o];
    return;
  }
  // ---- gcell fin: NG*32 = 640,000 = 1250*512 exact ----
  for (int k = threadIdx.x; k < 1024; k += 512) {
    Wa[k] = W_connect[k];
    Wb[k] = W_pt[k];
  }
  __syncthreads();
  int t = (b - 3750) * 512 + threadIdx.x;
  int r = t >> 5, o = t & 31;
  float a1 = 0.f, a2 = 0.f;
#pragma unroll 8
  for (int i = 0; i < 32; i++) {
    a1 += S_conn[(size_t)r * 32 + i] * Wa[i * 32 + o];
    a2 += S_pt[(size_t)r * 32 + i] * Wb[i * 32 + o];
  }
  out[1920000 + t] = a1 * rsqrtf(fmaxf((float)hist[10000 + r], 1.f)) + b_connect[o] +
                     a2 * rsqrtf(fmaxf((float)hist[30000 + r], 1.f)) + b_pt[o];
}

extern "C" void kernel_launch(void* const* d_in, const int* in_sizes, int n_in,
                              void* d_out, int out_size, void* d_ws, size_t ws_size,
                              hipStream_t stream) {
  const float* node_feat  = (const float*)d_in[0];
  const float* net_feat   = (const float*)d_in[1];
  const float* pin_feat   = (const float*)d_in[2];
  const float* hanna_feat = (const float*)d_in[3];
  const float* edge_feat  = (const float*)d_in[4];
  const int* pins_src    = (const int*)d_in[5];
  const int* pins_dst    = (const int*)d_in[6];
  const int* pinned_src  = (const int*)d_in[7];
  const int* pinned_dst  = (const int*)d_in[8];
  const int* connect_src = (const int*)d_in[9];
  const int* connect_dst = (const int*)d_in[10];
  const int* pt_src      = (const int*)d_in[11];
  const int* pt_dst      = (const int*)d_in[12];
  const int* pf_src      = (const int*)d_in[13];
  const int* pf_dst      = (const int*)d_in[14];
  const float* W_net     = (const float*)d_in[15];
  const float* b_net     = (const float*)d_in[16];
  const float* W_topo    = (const float*)d_in[17];
  const float* b_topo    = (const float*)d_in[18];
  const float* W_pins    = (const float*)d_in[19];
  const float* b_pins    = (const float*)d_in[20];
  const float* W_connect = (const float*)d_in[21];
  const float* b_connect = (const float*)d_in[22];
  const float* W_pt      = (const float*)d_in[23];
  const float* b_pt      = (const float*)d_in[24];
  const float* b_pinned  = (const float*)d_in[25];
  const float* b_pf      = (const float*)d_in[26];
  float* out = (float*)d_out;

  // ---- workspace layout (47.24 MB total; < proven 48.44 MB) ----
  int* wi = (int*)d_ws;
  int* hist    = wi + 0;          // [0, 150016)
  int* cursor  = wi + 150016;     // [150016, 300032)
  int* srccnt  = wi + 300032;     // [300032, 420032)
  int* bases   = wi + 420032;     // [420032, 570064)
  int* bsum    = wi + 570064;     // [570064, 570192)
  int2* csr_gc = (int2*)(wi + 570192);   // 300,000 * 8B  -> int end 1,170,192
  int2* csr_nn = (int2*)(wi + 1170192);  // 200,000 * 8B  -> int end 1,570,192
  float* wf = (float*)d_ws;
  float* S_net  = wf + 1570192;   // NN*32
  float* S_conn = wf + 1890192;   // NG*32
  float* S_pt   = wf + 2530192;   // NG*32
  float* C_net  = wf + 3170192;   // NN*32
  float* C_han  = wf + 3490192;   // NG*32 -> float end 4,130,192 (byte 16,520,768)
  u16* T_net = (u16*)((char*)d_ws + 16520832);             // NN*512 bf16
  u16* T_han = (u16*)((char*)d_ws + 16520832 + 10240000);  // NG*512 bf16
  // end byte: 47,240,832

  hipMemsetAsync(d_ws, 0, 420032 * sizeof(int), stream);  // hist+cursor+srccnt

  k_front<<<2540, 512, 0, stream>>>(
      net_feat, hanna_feat, W_topo, b_topo, T_net, T_han, C_net, C_han,
      pins_src, pins_dst, pinned_dst, pf_dst, connect_src, connect_dst,
      pt_src, pt_dst, hist, srccnt);

  k_scan1<<<NBLK, 256, 0, stream>>>(hist, bsum);
  k_scan3<<<NBLK, 256, 0, stream>>>(hist, bsum, bases);

  k_fill<<<(5 * NE + 511) / 512, 512, 0, stream>>>(
      pins_src, pins_dst, connect_src, connect_dst, pt_src, pt_dst,
      pinned_src, pinned_dst, pf_src, pf_dst, srccnt, bases, cursor,
      csr_gc, csr_nn);

  k_gc_gather<<<3125, 512, 0, stream>>>(
      hist, bases, csr_gc, node_feat, hanna_feat, S_net, S_conn, S_pt);

  k_tail<<<5000, 512, 0, stream>>>(
      hist, bases, csr_nn, pin_feat, edge_feat,
      T_net, T_han, C_net, C_han, b_pinned, b_pf,
      S_net, net_feat, W_pins, b_pins, W_net, b_net,
      S_conn, S_pt, W_connect, b_connect, W_pt, b_pt, out);
}

// Round 2
// 280.967 us; speedup vs baseline: 1.0170x; 1.0170x over previous
//
#include <hip/hip_runtime.h>

typedef unsigned short u16;
typedef unsigned int u32;

#define NC 50000
#define NN 10000
#define NG 20000
#define NE 100000
#define NSCAN 150016   // 5 dst-count regions (150,000) padded
#define NBLK 74        // ceil(NSCAN / 2048)

// CSR dst regions inside hist/bases (element offsets):
// pins_dst    [0,      10000)   -> net rows    (gc payload)
// connect_dst [10000,  30000)   -> gcell rows  (gc payload)
// pt_dst      [30000,  50000)   -> gcell rows  (gc payload)
// pinned_dst  [50000, 100000)   -> cell rows   (nn payload, pos-300000)
// pf_dst      [100000,150000)   -> cell rows   (nn payload, pos-300000)

// ---------- bf16 helpers (workspace T tables only) ----------
__device__ __forceinline__ float bflo(u32 a) { return __uint_as_float(a << 16); }
__device__ __forceinline__ float bfhi(u32 a) { return __uint_as_float(a & 0xFFFF0000u); }
__device__ __forceinline__ u16 fbf(float f) {
  u32 u = __float_as_uint(f);
  return (u16)((u + 0x7FFFu + ((u >> 16) & 1u)) >> 16);  // RNE
}

// one NNConv edge message for lane-output o
__device__ __forceinline__ float nn_msg(int e, int s, const float* __restrict__ ef,
                                        const u16* __restrict__ T,
                                        const float* __restrict__ C, int o) {
  const float4* efp = reinterpret_cast<const float4*>(ef + (size_t)e * 16);
  float4 ea = efp[0], eb = efp[1], ec = efp[2], ed = efp[3];
  const uint4* tp = reinterpret_cast<const uint4*>(T + (size_t)s * 512 + o * 16);
  uint4 ta = tp[0], tb = tp[1];
  float m = C[(size_t)s * 32 + o];
  m += ea.x * bflo(ta.x) + ea.y * bfhi(ta.x) + ea.z * bflo(ta.y) + ea.w * bfhi(ta.y);
  m += eb.x * bflo(ta.z) + eb.y * bfhi(ta.z) + eb.z * bflo(ta.w) + eb.w * bfhi(ta.w);
  m += ec.x * bflo(tb.x) + ec.y * bfhi(tb.x) + ec.z * bflo(tb.y) + ec.w * bfhi(tb.y);
  m += ed.x * bflo(tb.z) + ed.y * bfhi(tb.z) + ed.z * bflo(tb.w) + ed.w * bfhi(tb.w);
  return m;
}

// ---------- K_FRONT: transform (469) | C (1875) | hist (196) ----------
// transform: register-blocked GEMM tile, 64 nodes/block, 2 j-outputs/thread.
//   LDS-staged h tile (one sync), w in 64 VGPRs, FMA-bound inner loop.
// __launch_bounds__(512, 2): min 2 waves/EU -> VGPR cap 256, so the 64
//   unrolled weight values stay register-resident (was squeezed to 48 VGPRs
//   -> per-FMA W reloads -> VALUBusy 19%).
__global__ __launch_bounds__(512, 2) void k_front(
    const float* __restrict__ feat_net, const float* __restrict__ feat_han,
    const float* __restrict__ W_topo, const float* __restrict__ b_topo,
    u16* __restrict__ T_net, u16* __restrict__ T_han,
    float* __restrict__ C_net, float* __restrict__ C_han,
    const int* __restrict__ pins_src, const int* __restrict__ pins_dst,
    const int* __restrict__ pinned_dst, const int* __restrict__ pf_dst,
    const int* __restrict__ connect_src, const int* __restrict__ connect_dst,
    const int* __restrict__ pt_src, const int* __restrict__ pt_dst,
    int* __restrict__ hist, int* __restrict__ srccnt) {
  int b = blockIdx.x;
  int tid = threadIdx.x;
  if (b < 469) {  // ---- transform: nodes [b*64, b*64+64) of 30000 ----
    __shared__ float hs[64][32];  // 8 KB
    int nd0 = b * 64;
    {  // stage: thread t loads float4 at element t*4 of the 64x32 tile
      int idx = tid * 4;
      int nl = idx >> 5, i = idx & 31;
      int ng = nd0 + nl;
      int ngc = min(ng, 29999);  // clamp (rows >= 30000 unused)
      const float* rp = (ngc < NN) ? feat_net + (size_t)ngc * 32
                                   : feat_han + (size_t)(ngc - NN) * 32;
      *reinterpret_cast<float4*>(&hs[nl][i]) =
          *reinterpret_cast<const float4*>(rp + i);
    }
    // w regs for j0 = 2*(tid&255), j1 = j0+1
    int jj = tid & 255;
    int j0 = jj * 2, j1 = j0 + 1;
    int p0 = j0 & 15, o0 = j0 >> 4;
    int p1 = j1 & 15, o1 = j1 >> 4;
    float w0[32], w1[32];
#pragma unroll
    for (int i = 0; i < 32; i++) {
      w0[i] = W_topo[p0 * 1024 + i * 32 + o0];
      w1[i] = W_topo[p1 * 1024 + i * 32 + o1];
    }
    __syncthreads();
    int g = tid >> 8;  // node half: 0 or 1 (wave-uniform)
#pragma unroll 4
    for (int n = 0; n < 32; n++) {
      int nl = g * 32 + n;
      float a0 = 0.f, a1 = 0.f;
#pragma unroll
      for (int i = 0; i < 32; i++) {
        float h = hs[nl][i];  // wave-uniform -> LDS broadcast
        a0 += h * w0[i];
        a1 += h * w1[i];
      }
      int s = nd0 + nl;
      if (s < 30000) {
        u32 pk = (u32)fbf(a0) | ((u32)fbf(a1) << 16);
        u32* dst = (s < NN)
            ? reinterpret_cast<u32*>(T_net + (size_t)s * 512 + j0)
            : reinterpret_cast<u32*>(T_han + (size_t)(s - NN) * 512 + j0);
        *dst = pk;
      }
    }
    return;
  }
  if (b < 2344) {  // ---- C: (NN+NG)*32 = 960,000 = 1875*512 exact ----
    int t = (b - 469) * 512 + tid;
    int s2 = t >> 5, o = t & 31;
    bool han = s2 >= NN;
    const float* feat = han ? feat_han : feat_net;
    float* C = han ? C_han : C_net;
    int s = han ? s2 - NN : s2;
    float acc = 0.f;
#pragma unroll 8
    for (int i = 0; i < 32; i++)
      acc += feat[(size_t)s * 32 + i] * b_topo[i * 32 + o];
    C[(size_t)s * 32 + o] = acc;
    return;
  }
  // ---- hist ----
  int e = (b - 2344) * 512 + tid;
  if (e >= NE) return;
  atomicAdd(&hist[pins_dst[e]], 1);
  atomicAdd(&hist[10000 + connect_dst[e]], 1);
  atomicAdd(&hist[30000 + pt_dst[e]], 1);
  atomicAdd(&hist[50000 + pinned_dst[e]], 1);
  atomicAdd(&hist[100000 + pf_dst[e]], 1);
  atomicAdd(&srccnt[pins_src[e]], 1);            // cell  [0,50000)
  atomicAdd(&srccnt[50000 + connect_src[e]], 1); // gcell [50000,70000)
  atomicAdd(&srccnt[70000 + pt_src[e]], 1);      // cell  [70000,120000)
}

// ---------- scan (2 kernels) ----------
__global__ __launch_bounds__(256) void k_scan1(
    const int* __restrict__ cnt, int* __restrict__ bsum) {
  __shared__ int sm[256];
  int b = blockIdx.x, tid = threadIdx.x;
  int base = b * 2048 + tid * 8;
  int tot = 0;
#pragma unroll
  for (int j = 0; j < 8; j++) {
    int i = base + j;
    tot += (i < NSCAN) ? cnt[i] : 0;
  }
  sm[tid] = tot;
  __syncthreads();
  for (int off = 128; off > 0; off >>= 1) {
    if (tid < off) sm[tid] += sm[tid + off];
    __syncthreads();
  }
  if (tid == 0) bsum[b] = sm[0];
}

__global__ __launch_bounds__(256) void k_scan3(
    const int* __restrict__ cnt, const int* __restrict__ bsum,
    int* __restrict__ bases) {
  __shared__ int sm[256];
  __shared__ int carry;
  int b = blockIdx.x, tid = threadIdx.x;
  if (tid == 0) {
    int run = 0;
    for (int i = 0; i < b; i++) run += bsum[i];
    carry = run;
  }
  int base = b * 2048 + tid * 8;
  int v[8];
  int tot = 0;
#pragma unroll
  for (int j = 0; j < 8; j++) {
    int i = base + j;
    v[j] = (i < NSCAN) ? cnt[i] : 0;
    tot += v[j];
  }
  sm[tid] = tot;
  __syncthreads();
  for (int off = 1; off < 256; off <<= 1) {
    int add = (tid >= off) ? sm[tid - off] : 0;
    __syncthreads();
    sm[tid] += add;
    __syncthreads();
  }
  int excl = sm[tid] - tot + carry;
#pragma unroll
  for (int j = 0; j < 8; j++) {
    int i = base + j;
    if (i < NSCAN) bases[i] = excl;
    excl += v[j];
  }
}

// ---------- K_FILL: payload CSRs ----------
// gc (rel 0..2): csr_gc[pos] = (src, bits(rsqrt(deg_src)))   -- 8B sequential payload
// nn (rel 3..4): csr_nn[pos-300000] = (e, src)
__global__ __launch_bounds__(512) void k_fill(
    const int* __restrict__ pins_src, const int* __restrict__ pins_dst,
    const int* __restrict__ connect_src, const int* __restrict__ connect_dst,
    const int* __restrict__ pt_src, const int* __restrict__ pt_dst,
    const int* __restrict__ pinned_src, const int* __restrict__ pinned_dst,
    const int* __restrict__ pf_src, const int* __restrict__ pf_dst,
    const int* __restrict__ srccnt,
    const int* __restrict__ bases, int* __restrict__ cursor,
    int2* __restrict__ csr_gc, int2* __restrict__ csr_nn) {
  int t = blockIdx.x * 512 + threadIdx.x;
  if (t >= 5 * NE) return;
  int r = (t >= NE) + (t >= 2 * NE) + (t >= 3 * NE) + (t >= 4 * NE);
  int e = t - r * NE;
  const int* srcs = r == 0 ? pins_src : r == 1 ? connect_src
                   : r == 2 ? pt_src : r == 3 ? pinned_src : pf_src;
  const int* dsts = r == 0 ? pins_dst : r == 1 ? connect_dst
                   : r == 2 ? pt_dst : r == 3 ? pinned_dst : pf_dst;
  int off = r == 0 ? 0 : r == 1 ? 10000 : r == 2 ? 30000 : r == 3 ? 50000 : 100000;
  int s = srcs[e];
  int g = off + dsts[e];
  int pos = atomicAdd(&cursor[g], 1);
  int cpos = bases[g] + pos;
  if (r < 3) {
    int soff = r == 0 ? 0 : r == 1 ? 50000 : 70000;
    float w = rsqrtf(fmaxf((float)srccnt[soff + s], 1.f));
    csr_gc[cpos] = make_int2(s, __float_as_int(w));
  } else {
    csr_nn[cpos - 300000] = make_int2(e, s);
  }
}

// ---------- K_GC: graph-conv gather (payload CSR: 1 random load/edge) ----------
__global__ __launch_bounds__(512) void k_gc_gather(
    const int* __restrict__ hist, const int* __restrict__ bases,
    const int2* __restrict__ csr_gc,
    const float* __restrict__ node_feat, const float* __restrict__ hanna_feat,
    float* __restrict__ S_net, float* __restrict__ S_conn, float* __restrict__ S_pt) {
  int t = blockIdx.x * 512 + threadIdx.x;  // 3125*512 = 1.6M exact
  int rr = t >> 5, o = t & 31;
  int rel = (rr >= 10000) + (rr >= 30000);
  const float* feat = (rel == 1) ? hanna_feat : node_feat;
  float* S = rel == 0 ? S_net + (size_t)rr * 32
           : rel == 1 ? S_conn + (size_t)(rr - 10000) * 32
                      : S_pt + (size_t)(rr - 30000) * 32;
  int base = bases[rr], deg = hist[rr];
  float acc = 0.f;
  int k = 0;
  for (; k + 1 < deg; k += 2) {
    int2 pa = csr_gc[base + k], pb = csr_gc[base + k + 1];
    acc += feat[(size_t)pa.x * 32 + o] * __int_as_float(pa.y) +
           feat[(size_t)pb.x * 32 + o] * __int_as_float(pb.y);
  }
  if (k < deg) {
    int2 pa = csr_gc[base + k];
    acc += feat[(size_t)pa.x * 32 + o] * __int_as_float(pa.y);
  }
  S[o] = acc;
}

// ---------- K_TAIL: nn_gather cells (3125) | net fin (625) | gcell fin (1250) ----------
__global__ __launch_bounds__(512) void k_tail(
    const int* __restrict__ hist, const int* __restrict__ bases,
    const int2* __restrict__ csr_nn,
    const float* __restrict__ pin_feat, const float* __restrict__ edge_feat,
    const u16* __restrict__ T_net, const u16* __restrict__ T_han,
    const float* __restrict__ C_net, const float* __restrict__ C_han,
    const float* __restrict__ b_pinned, const float* __restrict__ b_pf,
    const float* __restrict__ S_net, const float* __restrict__ net_feat,
    const float* __restrict__ W_pins, const float* __restrict__ b_pins,
    const float* __restrict__ W_net, const float* __restrict__ b_net,
    const float* __restrict__ S_conn, const float* __restrict__ S_pt,
    const float* __restrict__ W_connect, const float* __restrict__ b_connect,
    const float* __restrict__ W_pt, const float* __restrict__ b_pt,
    float* __restrict__ out) {
  __shared__ float Wa[1024], Wb[1024];
  int b = blockIdx.x;
  if (b < 3125) {  // ---- NNConv gather: NC*32 = 1.6M = 3125*512 exact ----
    int t = b * 512 + threadIdx.x;
    int d = t >> 5, o = t & 31;
    float a0 = 0.f, a1 = 0.f;
    {  // conv0: 'pinned' net -> cell
      int g = 50000 + d;
      int base = bases[g] - 300000, deg = hist[g];
      int k = 0;
      for (; k + 1 < deg; k += 2) {
        int2 ea = csr_nn[base + k], eb = csr_nn[base + k + 1];
        a0 += nn_msg(ea.x, ea.y, pin_feat, T_net, C_net, o) +
              nn_msg(eb.x, eb.y, pin_feat, T_net, C_net, o);
      }
      if (k < deg) {
        int2 ea = csr_nn[base + k];
        a0 += nn_msg(ea.x, ea.y, pin_feat, T_net, C_net, o);
      }
      a0 /= fmaxf((float)deg, 1.f);
    }
    {  // conv1: 'point-from' gcell -> cell
      int g = 100000 + d;
      int base = bases[g] - 300000, deg = hist[g];
      int k = 0;
      for (; k + 1 < deg; k += 2) {
        int2 ea = csr_nn[base + k], eb = csr_nn[base + k + 1];
        a1 += nn_msg(ea.x, ea.y, edge_feat, T_han, C_han, o) +
              nn_msg(eb.x, eb.y, edge_feat, T_han, C_han, o);
      }
      if (k < deg) {
        int2 ea = csr_nn[base + k];
        a1 += nn_msg(ea.x, ea.y, edge_feat, T_han, C_han, o);
      }
      a1 /= fmaxf((float)deg, 1.f);
    }
    out[(size_t)d * 32 + o] = a0 + a1 + b_pinned[o] + b_pf[o];
    return;
  }
  if (b < 3750) {  // ---- net fin: NN*32 = 320,000 = 625*512 exact ----
    for (int k = threadIdx.x; k < 1024; k += 512) {
      Wa[k] = W_pins[k];
      Wb[k] = W_net[k];
    }
    __syncthreads();
    int t = (b - 3125) * 512 + threadIdx.x;
    int r = t >> 5, o = t & 31;
    float a1 = 0.f, a2 = 0.f;
#pragma unroll 8
    for (int i = 0; i < 32; i++) {
      a1 += S_net[(size_t)r * 32 + i] * Wa[i * 32 + o];
      a2 += net_feat[(size_t)r * 32 + i] * Wb[i * 32 + o];
    }
    out[1600000 + t] = a1 * rsqrtf(fmaxf((float)hist[r], 1.f)) + b_pins[o] +
                       a2 + b_net[o];
    return;
  }
  // ---- gcell fin: NG*32 = 640,000 = 1250*512 exact ----
  for (int k = threadIdx.x; k < 1024; k += 512) {
    Wa[k] = W_connect[k];
    Wb[k] = W_pt[k];
  }
  __syncthreads();
  int t = (b - 3750) * 512 + threadIdx.x;
  int r = t >> 5, o = t & 31;
  float a1 = 0.f, a2 = 0.f;
#pragma unroll 8
  for (int i = 0; i < 32; i++) {
    a1 += S_conn[(size_t)r * 32 + i] * Wa[i * 32 + o];
    a2 += S_pt[(size_t)r * 32 + i] * Wb[i * 32 + o];
  }
  out[1920000 + t] = a1 * rsqrtf(fmaxf((float)hist[10000 + r], 1.f)) + b_connect[o] +
                     a2 * rsqrtf(fmaxf((float)hist[30000 + r], 1.f)) + b_pt[o];
}

extern "C" void kernel_launch(void* const* d_in, const int* in_sizes, int n_in,
                              void* d_out, int out_size, void* d_ws, size_t ws_size,
                              hipStream_t stream) {
  const float* node_feat  = (const float*)d_in[0];
  const float* net_feat   = (const float*)d_in[1];
  const float* pin_feat   = (const float*)d_in[2];
  const float* hanna_feat = (const float*)d_in[3];
  const float* edge_feat  = (const float*)d_in[4];
  const int* pins_src    = (const int*)d_in[5];
  const int* pins_dst    = (const int*)d_in[6];
  const int* pinned_src  = (const int*)d_in[7];
  const int* pinned_dst  = (const int*)d_in[8];
  const int* connect_src = (const int*)d_in[9];
  const int* connect_dst = (const int*)d_in[10];
  const int* pt_src      = (const int*)d_in[11];
  const int* pt_dst      = (const int*)d_in[12];
  const int* pf_src      = (const int*)d_in[13];
  const int* pf_dst      = (const int*)d_in[14];
  const float* W_net     = (const float*)d_in[15];
  const float* b_net     = (const float*)d_in[16];
  const float* W_topo    = (const float*)d_in[17];
  const float* b_topo    = (const float*)d_in[18];
  const float* W_pins    = (const float*)d_in[19];
  const float* b_pins    = (const float*)d_in[20];
  const float* W_connect = (const float*)d_in[21];
  const float* b_connect = (const float*)d_in[22];
  const float* W_pt      = (const float*)d_in[23];
  const float* b_pt      = (const float*)d_in[24];
  const float* b_pinned  = (const float*)d_in[25];
  const float* b_pf      = (const float*)d_in[26];
  float* out = (float*)d_out;

  // ---- workspace layout (47.24 MB total; < proven 48.44 MB) ----
  int* wi = (int*)d_ws;
  int* hist    = wi + 0;          // [0, 150016)
  int* cursor  = wi + 150016;     // [150016, 300032)
  int* srccnt  = wi + 300032;     // [300032, 420032)
  int* bases   = wi + 420032;     // [420032, 570064)
  int* bsum    = wi + 570064;     // [570064, 570192)
  int2* csr_gc = (int2*)(wi + 570192);   // 300,000 * 8B  -> int end 1,170,192
  int2* csr_nn = (int2*)(wi + 1170192);  // 200,000 * 8B  -> int end 1,570,192
  float* wf = (float*)d_ws;
  float* S_net  = wf + 1570192;   // NN*32
  float* S_conn = wf + 1890192;   // NG*32
  float* S_pt   = wf + 2530192;   // NG*32
  float* C_net  = wf + 3170192;   // NN*32
  float* C_han  = wf + 3490192;   // NG*32 -> float end 4,130,192 (byte 16,520,768)
  u16* T_net = (u16*)((char*)d_ws + 16520832);             // NN*512 bf16
  u16* T_han = (u16*)((char*)d_ws + 16520832 + 10240000);  // NG*512 bf16
  // end byte: 47,240,832

  hipMemsetAsync(d_ws, 0, 420032 * sizeof(int), stream);  // hist+cursor+srccnt

  k_front<<<2540, 512, 0, stream>>>(
      net_feat, hanna_feat, W_topo, b_topo, T_net, T_han, C_net, C_han,
      pins_src, pins_dst, pinned_dst, pf_dst, connect_src, connect_dst,
      pt_src, pt_dst, hist, srccnt);

  k_scan1<<<NBLK, 256, 0, stream>>>(hist, bsum);
  k_scan3<<<NBLK, 256, 0, stream>>>(hist, bsum, bases);

  k_fill<<<(5 * NE + 511) / 512, 512, 0, stream>>>(
      pins_src, pins_dst, connect_src, connect_dst, pt_src, pt_dst,
      pinned_src, pinned_dst, pf_src, pf_dst, srccnt, bases, cursor,
      csr_gc, csr_nn);

  k_gc_gather<<<3125, 512, 0, stream>>>(
      hist, bases, csr_gc, node_feat, hanna_feat, S_net, S_conn, S_pt);

  k_tail<<<5000, 512, 0, stream>>>(
      hist, bases, csr_nn, pin_feat, edge_feat,
      T_net, T_han, C_net, C_han, b_pinned, b_pf,
      S_net, net_feat, W_pins, b_pins, W_net, b_net,
      S_conn, S_pt, W_connect, b_connect, W_pt, b_pt, out);
}